// Round 16
// baseline (225.568 us; speedup 1.0000x reference)
//
#include <hip/hip_runtime.h>

// ---- problem constants ----
#define B_    2
#define N_    2049
#define NPAD  2112          // keys padded to multiple of 64
#define D_    1024
#define H_    16
#define DH    64
#define MROWS (B_ * N_)     // 4098
#define MPAD  4224          // = 2*NPAD: per-batch padded row space [b][NPAD]
#define QSCALE 0.18033688011117674f   // 0.125 * log2(e): softmax in exp2 domain
#define NKT   33            // 33 key tiles of 64 cover NPAD

using bf16x8 = __attribute__((ext_vector_type(8))) short;
using f32x4  = __attribute__((ext_vector_type(4))) float;
using f32x16 = __attribute__((ext_vector_type(16))) float;

#define AS1 __attribute__((address_space(1)))
#define AS3 __attribute__((address_space(3)))

__device__ __forceinline__ float bf2f(short s) {
  union { unsigned u; float f; } a; a.u = ((unsigned)(unsigned short)s) << 16; return a.f;
}
__device__ __forceinline__ short f2bf(float f) {
  union { float f; unsigned u; } a; a.f = f;
  unsigned r = a.u + 0x7fffu + ((a.u >> 16) & 1u);   // round-to-nearest-even
  return (short)(r >> 16);
}
// hardware 2^x (v_exp_f32)
__device__ __forceinline__ float hexp2(float x) { return __builtin_amdgcn_exp2f(x); }
// async global->LDS DMA, 16 B/lane; LDS dst is wave-uniform base (+lane*16 by HW)
__device__ __forceinline__ void dma16(const short* g, AS3 short* l) {
  __builtin_amdgcn_global_load_lds((const AS1 unsigned*)g, (AS3 unsigned*)l, 16, 0, 0);
}

// ---- panel-tiled layout for GEMM operands (K=1024 fixed) ----
// X[m][k] -> [m>>7][k>>5][(m&127)>>4][((m&15)<<2)|((k&31)>>3)][k&7]
__device__ __forceinline__ size_t tiled_off(int m, int k) {
  return ((size_t)(m >> 7) << 17)                       // panel: 128*1024 shorts
       + (size_t)(((k >> 5) << 12)                      // kt chunk: 4096 shorts
       + ((((m & 127) >> 4)) << 9)                      // j slab: 512 shorts
       + (((((m & 15) << 2) | ((k & 31) >> 3))) << 3)   // lane slot: 8 shorts
       + (k & 7));
}

// ------------- prep: ln (4098 blks) + transpose wqkv (768) + transpose wout (256) --------
__global__ __launch_bounds__(256) void prep_kernel(const float* __restrict__ x,
                                                   const float* __restrict__ gamma,
                                                   const float* __restrict__ beta,
                                                   short* __restrict__ xn,
                                                   const float* __restrict__ w_qkv,
                                                   short* __restrict__ wqkvT,
                                                   const float* __restrict__ w_out,
                                                   short* __restrict__ woutT) {
  int blk = blockIdx.x;
  int tid = threadIdx.x;
  __shared__ float T[64][65];
  __shared__ float sb[4], s2b[4];

  if (blk < MROWS) {
    // ---- LayerNorm row ----
    int row = blk;
    int b = row >= N_;
    int rowp = b * NPAD + (row - b * N_);
    const float4 v = ((const float4*)(x + (size_t)row * D_))[tid];
    float s  = v.x + v.y + v.z + v.w;
    float ss = v.x * v.x + v.y * v.y + v.z * v.z + v.w * v.w;
    for (int o = 1; o < 64; o <<= 1) { s += __shfl_xor(s, o, 64); ss += __shfl_xor(ss, o, 64); }
    int wid = tid >> 6;
    if ((tid & 63) == 0) { sb[wid] = s; s2b[wid] = ss; }
    __syncthreads();
    float st  = sb[0] + sb[1] + sb[2] + sb[3];
    float sst = s2b[0] + s2b[1] + s2b[2] + s2b[3];
    float mu  = st * (1.0f / D_);
    float var = sst * (1.0f / D_) - mu * mu;
    float rs  = rsqrtf(var + 1e-5f);
    const float4 g  = ((const float4*)gamma)[tid];
    const float4 be = ((const float4*)beta)[tid];
    short4 o4;
    o4.x = f2bf((v.x - mu) * rs * g.x + be.x);
    o4.y = f2bf((v.y - mu) * rs * g.y + be.y);
    o4.z = f2bf((v.z - mu) * rs * g.z + be.z);
    o4.w = f2bf((v.w - mu) * rs * g.w + be.w);
    *(short4*)(xn + tiled_off(rowp, tid * 4)) = o4;   // tiled write (8B, aligned)
    return;
  }

  // ---- transpose+cast: fp32 [K][Nn] -> bf16 tiled [Nn][K], 64x64 LDS tile ----
  const float* in; short* out; int Nn, t2;
  int b2 = blk - MROWS;
  if (b2 < 768) { in = w_qkv; out = wqkvT; Nn = 3072; t2 = b2; }
  else          { in = w_out; out = woutT; Nn = 1024; t2 = b2 - 768; }
  int k0 = (t2 & 15) * 64;          // 1024/64 = 16 tiles along K
  int n0 = (t2 >> 4) * 64;
  int r = tid >> 2, c0 = (tid & 3) * 16;
  const float* ip = in + (size_t)(k0 + r) * Nn + n0 + c0;
  #pragma unroll
  for (int j = 0; j < 4; ++j) {
    float4 v = *(const float4*)(ip + j * 4);
    T[r][c0 + j * 4 + 0] = v.x; T[r][c0 + j * 4 + 1] = v.y;
    T[r][c0 + j * 4 + 2] = v.z; T[r][c0 + j * 4 + 3] = v.w;
  }
  __syncthreads();
  bf16x8 w0, w1;
  #pragma unroll
  for (int j = 0; j < 8; ++j) {
    w0[j] = f2bf(T[c0 + j][r]);
    w1[j] = f2bf(T[c0 + 8 + j][r]);
  }
  *(bf16x8*)(out + tiled_off(n0 + r, k0 + c0))     = w0;   // tiled writes (16B, aligned)
  *(bf16x8*)(out + tiled_off(n0 + r, k0 + c0 + 8)) = w1;
}

// ------------- fused QKV GEMM + RoPE + fragment emission (r13-exact) -------------
#define BM 128
#define BK 32
__global__ __launch_bounds__(256) void gemm_qkv_rope(const short* __restrict__ A,
                                                     const short* __restrict__ BT,
                                                     short* __restrict__ qg,
                                                     short* __restrict__ kfrag,
                                                     short* __restrict__ vfrag) {
  int lane = threadIdx.x & 63, wid = threadIdx.x >> 6;
  int quad = lane >> 4, l16 = lane & 15;
  int wr = wid >> 1, wc = wid & 1;
  int chunk = gridDim.x >> 3;
  int swz = (blockIdx.x & 7) * chunk + (blockIdx.x >> 3);
  int mb = swz % 33, nb = swz / 33;     // nb 0..23
  int m0 = mb * BM;
  int n0 = nb * BM;

  __shared__ __align__(16) short pool[17408];   // mainloop: A[2][4096]+B[2][4096]; epi: Ct[128][136]
  AS3 short* AbufL = (AS3 short*)pool;
  AS3 short* BbufL = (AS3 short*)(pool + 8192);
  const short* AbufR = pool;
  const short* BbufR = pool + 8192;

  f32x4 acc[4][4] = {};

  const short* Ap = A  + ((size_t)(m0 >> 7) << 17);   // panel bases
  const short* Bp = BT + ((size_t)(n0 >> 7) << 17);

  auto stage = [&](int kt, int bb) {
    #pragma unroll
    for (int i = 0; i < 2; ++i) {
      int j = wid * 2 + i;                  // slab 0..7 (16 rows each)
      dma16(Ap + ((size_t)kt << 12) + j * 512 + lane * 8, AbufL + bb * 4096 + j * 512);
      dma16(Bp + ((size_t)kt << 12) + j * 512 + lane * 8, BbufL + bb * 4096 + j * 512);
    }
  };

  stage(0, 0);
  __syncthreads();

  for (int kt = 0; kt < 32; ++kt) {
    int cur = kt & 1;
    if (kt + 1 < 32) stage(kt + 1, cur ^ 1);
    const short* Ab = AbufR + cur * 4096;
    const short* Bb = BbufR + cur * 4096;
    bf16x8 af[4], bfr[4];
    #pragma unroll
    for (int s = 0; s < 4; ++s)
      af[s] = *(const bf16x8*)&Ab[(wr * 64 + s * 16 + l16) * BK + quad * 8];
    #pragma unroll
    for (int t = 0; t < 4; ++t)
      bfr[t] = *(const bf16x8*)&Bb[(wc * 64 + t * 16 + l16) * BK + quad * 8];
    #pragma unroll
    for (int s = 0; s < 4; ++s)
      #pragma unroll
      for (int t = 0; t < 4; ++t)
        acc[s][t] = __builtin_amdgcn_mfma_f32_16x16x32_bf16(af[s], bfr[t], acc[s][t], 0, 0, 0);
    __syncthreads();
  }

  // ---- stage C tile (bf16) to LDS: Ct[row][col], stride 136 shorts ----
  short* Ct = pool;     // A/B buffers dead after final barrier
  #pragma unroll
  for (int s = 0; s < 4; ++s)
    #pragma unroll
    for (int t = 0; t < 4; ++t) {
      int col = wc * 64 + t * 16 + l16;
      #pragma unroll
      for (int r = 0; r < 4; ++r) {
        int row = wr * 64 + s * 16 + quad * 4 + r;
        Ct[row * 136 + col] = f2bf(acc[s][t][r]);
      }
    }
  __syncthreads();

  int third = nb >> 3;            // 0=q 1=k 2=v
  int hpair = (nb & 7) * 2;       // head base (2 heads per block)
  int tid = threadIdx.x;

  if (third == 0) {
    // ---- Q: rope + scale, row-major qg[bh][n][dh] ----
    int p = tid & 3, nl = tid >> 2;
    #pragma unroll
    for (int tt = 0; tt < 2; ++tt) {
      int rl = tt * 64 + nl;
      int rg = m0 + rl;
      int b = rg >= NPAD;
      int n = rg - b * NPAD;
      bool valid = n < N_;
      bool rot = valid && n > 0;
      float csv[8], snv[8];
      #pragma unroll
      for (int j = 0; j < 8; ++j) {
        int i = p * 8 + j;
        float ang = rot ? (float)(n - 1) * hexp2((float)i * -0.4152410118609203f) : 0.0f;
        float rev = ang * 0.15915494309189535f;
        rev = rev - floorf(rev);
        snv[j] = rot ? __builtin_amdgcn_sinf(rev) : 0.0f;
        csv[j] = rot ? __builtin_amdgcn_cosf(rev) : 1.0f;
      }
      #pragma unroll
      for (int hh = 0; hh < 2; ++hh) {
        bf16x8 w1v = {}, w2v = {};
        if (valid) {
          bf16x8 va = *(const bf16x8*)&Ct[rl * 136 + hh * 64 + p * 8];
          bf16x8 vb = *(const bf16x8*)&Ct[rl * 136 + hh * 64 + p * 8 + 32];
          #pragma unroll
          for (int j = 0; j < 8; ++j) {
            float a = bf2f(va[j]), b2 = bf2f(vb[j]);
            w1v[j] = f2bf((a * csv[j] - b2 * snv[j]) * QSCALE);
            w2v[j] = f2bf((b2 * csv[j] + a * snv[j]) * QSCALE);
          }
        }
        size_t ob = ((size_t)(b * 16 + hpair + hh) * NPAD + n) * DH;
        *(bf16x8*)(qg + ob + p * 8)      = w1v;
        *(bf16x8*)(qg + ob + 32 + p * 8) = w2v;
      }
    }
  } else if (third == 1) {
    // ---- K: rope, fragment-linear ----
    int rl = tid & 127, hi = tid >> 7;
    int rg = m0 + rl;
    int b = rg >= NPAD;
    int n = rg - b * NPAD;
    bool valid = n < N_;
    bool rot = valid && n > 0;
    int kt = n >> 6, g = (n >> 5) & 1, lk = n & 31;
    int l = hi * 32 + lk;
    #pragma unroll
    for (int s2 = 0; s2 < 2; ++s2) {
      float csv[8], snv[8];
      #pragma unroll
      for (int j = 0; j < 8; ++j) {
        int i = s2 * 16 + hi * 8 + j;            // i in [0,32)
        float ang = rot ? (float)(n - 1) * hexp2((float)i * -0.4152410118609203f) : 0.0f;
        float rev = ang * 0.15915494309189535f;
        rev = rev - floorf(rev);
        snv[j] = rot ? __builtin_amdgcn_sinf(rev) : 0.0f;
        csv[j] = rot ? __builtin_amdgcn_cosf(rev) : 1.0f;
      }
      #pragma unroll
      for (int hh = 0; hh < 2; ++hh) {
        bf16x8 wlo = {}, whi = {};
        if (valid) {
          bf16x8 va = *(const bf16x8*)&Ct[rl * 136 + hh * 64 + s2 * 16 + hi * 8];
          bf16x8 vb = *(const bf16x8*)&Ct[rl * 136 + hh * 64 + s2 * 16 + hi * 8 + 32];
          #pragma unroll
          for (int j = 0; j < 8; ++j) {
            float a = bf2f(va[j]), b2 = bf2f(vb[j]);
            wlo[j] = f2bf(a * csv[j] - b2 * snv[j]);
            whi[j] = f2bf(b2 * csv[j] + a * snv[j]);
          }
        }
        short* base = kfrag + (size_t)(b * 16 + hpair + hh) * NPAD * DH + (size_t)kt * 4096;
        *(bf16x8*)(base + (g * 4 + s2) * 512 + l * 8)     = wlo;
        *(bf16x8*)(base + (g * 4 + s2 + 2) * 512 + l * 8) = whi;
      }
    }
  } else {
    // ---- V: fragment-linear ----
    int lk = tid & 31, z = tid >> 5;   // z 0..7
    #pragma unroll
    for (int oo = 0; oo < 2; ++oo) {
      int o = z * 2 + oo;              // key octet 0..15 within block
      int rg = m0 + o * 8;
      int b = rg >= NPAD;
      int n0o = rg - b * NPAD;         // octet-base key index (8-aligned)
      int kt = n0o >> 6;
      int s = (n0o >> 4) & 3;
      int hi = (n0o >> 3) & 1;
      #pragma unroll
      for (int hh = 0; hh < 2; ++hh) {
        short* base = vfrag + (size_t)(b * 16 + hpair + hh) * NPAD * DH + (size_t)kt * 4096;
        #pragma unroll
        for (int m = 0; m < 2; ++m) {
          bf16x8 wv = {};
          #pragma unroll
          for (int j = 0; j < 8; ++j)
            if (n0o + j < N_) wv[j] = Ct[(o * 8 + j) * 136 + hh * 64 + m * 32 + lk];
          *(bf16x8*)(base + (m * 4 + s) * 512 + (hi * 32 + lk) * 8) = wv;
        }
      }
    }
  }
}

// ------------- out-proj GEMM: 64x128 tiles, 528 blocks (neutral vs 264; kept) ------------
__global__ __launch_bounds__(256) void gemm_out(const short* __restrict__ A,
                                                const short* __restrict__ BT,
                                                float* __restrict__ C) {
  int lane = threadIdx.x & 63, wid = threadIdx.x >> 6;
  int quad = lane >> 4, l16 = lane & 15;
  int wr = wid >> 1, wc = wid & 1;
  int chunk = gridDim.x >> 3;
  int swz = (blockIdx.x & 7) * chunk + (blockIdx.x >> 3);
  int mb = swz % 66, nb = swz / 66;     // 66 x 8 tiles
  int m0 = mb * 64;
  int n0 = nb * 128;

  __shared__ __align__(16) short Abuf[2][2048];   // 64x32, 4 KB each
  __shared__ __align__(16) short Bbuf[2][4096];   // 128x32, 8 KB each
  AS3 short* AbufL = (AS3 short*)&Abuf[0][0];
  AS3 short* BbufL = (AS3 short*)&Bbuf[0][0];

  f32x4 acc[2][4] = {};

  const short* Ap = A  + ((size_t)(m0 >> 7) << 17);   // panel bases
  const short* Bp = BT + ((size_t)(n0 >> 7) << 17);
  int jbA = (m0 & 127) >> 4;                          // 0 or 4: slab base within panel

  auto stage = [&](int kt, int bb) {
    // A: 4 slabs, one per wave; B: 8 slabs, two per wave (3 DMA ops/wave/stage)
    dma16(Ap + ((size_t)kt << 12) + (jbA + wid) * 512 + lane * 8, AbufL + bb * 2048 + wid * 512);
    #pragma unroll
    for (int i = 0; i < 2; ++i) {
      int j = wid * 2 + i;
      dma16(Bp + ((size_t)kt << 12) + j * 512 + lane * 8, BbufL + bb * 4096 + j * 512);
    }
  };

  stage(0, 0);
  __syncthreads();

  for (int kt = 0; kt < 32; ++kt) {
    int cur = kt & 1;
    if (kt + 1 < 32) stage(kt + 1, cur ^ 1);
    const short* Ab = &Abuf[cur][0];
    const short* Bb = &Bbuf[cur][0];
    bf16x8 af[2], bfr[4];
    #pragma unroll
    for (int s = 0; s < 2; ++s)
      af[s] = *(const bf16x8*)&Ab[(wr * 32 + s * 16 + l16) * BK + quad * 8];
    #pragma unroll
    for (int t = 0; t < 4; ++t)
      bfr[t] = *(const bf16x8*)&Bb[(wc * 64 + t * 16 + l16) * BK + quad * 8];
    #pragma unroll
    for (int s = 0; s < 2; ++s)
      #pragma unroll
      for (int t = 0; t < 4; ++t)
        acc[s][t] = __builtin_amdgcn_mfma_f32_16x16x32_bf16(af[s], bfr[t], acc[s][t], 0, 0, 0);
    __syncthreads();
  }

  #pragma unroll
  for (int s = 0; s < 2; ++s)
    #pragma unroll
    for (int r = 0; r < 4; ++r) {
      int row = m0 + wr * 32 + s * 16 + quad * 4 + r;
      if (row < MROWS) {
        size_t rb = (size_t)row * 1024 + n0 + wc * 64;
        #pragma unroll
        for (int t = 0; t < 4; ++t)
          C[rb + t * 16 + l16] = acc[s][t][r];
      }
    }
}

// ------------- flash attention v13: r13 sync skeleton + T15 deferred-PV pipeline ---------
// The barrier/vmcnt schedule is byte-identical to r13 (proven load-bearing). Change: PV of
// tile kt-1 runs inside region kt, breaking the serial QK->softmax->PV chain into two
// independent chains the scheduler can interleave (MFMA pipe ~ VALU pipe overlap, T15).
// V becomes 4-deep buffered so region kt can still read V(kt-1): stage(kt+2) writes
// Vbuf[(kt+2)&3] != Vbuf[(kt-1)&3] (distinct mod 4). K stays 3-deep (reads in own region).
// P-fragments carried one region in registers via static wA/wB unroll-by-2 (+16 VGPR).
__global__ __launch_bounds__(256, 3) void attn_kernel(const short* __restrict__ qg,
                                                      const short* __restrict__ kfrag,
                                                      const short* __restrict__ vfrag,
                                                      short* __restrict__ out) {
  // XCD-clustered decode: blk&7 -> XCD; 4 heads per XCD
  int blk = blockIdx.x;             // 0..543
  int xcd = blk & 7;
  int t_  = blk >> 3;               // 0..67
  int bh  = xcd * 4 + (t_ & 3);
  int qblk = t_ >> 2;               // 0..16
  int b = bh >> 4, h = bh & 15;

  int lane = threadIdx.x & 63, wid = threadIdx.x >> 6;
  int q    = lane & 31;             // q-column within wave's 32-row tile
  int half = lane >> 5;             // 0/1: lane half
  int q0   = qblk * 128 + wid * 32;
  size_t hb = (size_t)bh * NPAD * DH;
  const short* kf_hb = kfrag + hb;
  const short* vf_hb = vfrag + hb;

  __shared__ __align__(16) short Kbuf[3][4096];   // 24 KB
  __shared__ __align__(16) short Vbuf[4][4096];   // 32 KB (4-deep for deferred PV)
  AS3 short* KbufL = (AS3 short*)&Kbuf[0][0];
  AS3 short* VbufL = (AS3 short*)&Vbuf[0][0];
  const short* KbufR = &Kbuf[0][0];
  const short* VbufR = &Vbuf[0][0];

  // Q B-frags (persistent): lane reads its q-row; k = kstep*16 + half*8 + j
  int qr = q0 + q; if (qr >= NPAD) qr = 0;   // clamp; garbage column never stored
  const short* qp = qg + hb + (size_t)qr * DH + half * 8;
  bf16x8 qf[4];
  #pragma unroll
  for (int s = 0; s < 4; ++s) qf[s] = *(const bf16x8*)(qp + s * 16);

  f32x16 o0 = {}, o1 = {};          // O^T[dh = m*32 + (reg&3)+8*(reg>>2)+4*half][q]
  float lrun = 0.0f;                // per-lane half-sum; cross-half fold at epilogue

  // K+V stage: fragment-linear, contiguous 1KiB sources. 4 ops/wave/stage.
  auto stage = [&](int kt) {
    const short* ksrc = kf_hb + (size_t)kt * 4096;
    const short* vsrc = vf_hb + (size_t)kt * 4096;
    #pragma unroll
    for (int i = 0; i < 2; ++i) {
      int j = wid * 2 + i;
      dma16(ksrc + j * 512 + lane * 8, KbufL + (kt % 3) * 4096 + j * 512);
      dma16(vsrc + j * 512 + lane * 8, VbufL + (kt & 3) * 4096 + j * 512);
    }
  };

  stage(0);                         // prefetch distance 2 (r13-identical)
  stage(1);

  unsigned wA[4][4], wB[4][4];      // P-frag carry, static roles via unroll-by-2

  // region kt: guard+barrier, stage(kt+2), QK(kt), softmax(kt) -> wc
  auto qkpart = [&](int kt, unsigned (&wc)[4][4]) {
    int k0 = kt * 64;
    if (kt == NKT - 1) asm volatile("s_waitcnt vmcnt(0)" ::: "memory");
    else               asm volatile("s_waitcnt vmcnt(4)" ::: "memory");
    __builtin_amdgcn_s_barrier();

    if (kt + 2 < NKT) stage(kt + 2);
    __builtin_amdgcn_sched_barrier(0);

    const short* Kc = KbufR + (kt % 3) * 4096;
    f32x16 sA = {}, sB = {};
    __builtin_amdgcn_s_setprio(1);
    #pragma unroll
    for (int s = 0; s < 4; ++s) {
      bf16x8 kf0 = *(const bf16x8*)&Kc[(0 * 4 + s) * 512 + lane * 8];
      bf16x8 kf1 = *(const bf16x8*)&Kc[(1 * 4 + s) * 512 + lane * 8];
      sA = __builtin_amdgcn_mfma_f32_32x32x16_bf16(kf0, qf[s], sA, 0, 0, 0);
      sB = __builtin_amdgcn_mfma_f32_32x32x16_bf16(kf1, qf[s], sB, 0, 0, 0);
    }
    __builtin_amdgcn_s_setprio(0);

    // mask invalid keys (final tile only; wave-uniform branch)
    if (k0 + 64 > N_) {
      #pragma unroll
      for (int rr = 0; rr < 16; ++rr) {
        int key = (rr & 3) + 8 * (rr >> 2) + 4 * half;
        if (k0 + key >= N_)      sA[rr] = -1e30f;
        if (k0 + 32 + key >= N_) sB[rr] = -1e30f;
      }
    }

    // p = 2^s + per-lane row-sum
    float vsum = 0.0f;
    #pragma unroll
    for (int rr = 0; rr < 16; ++rr) {
      sA[rr] = hexp2(sA[rr]); vsum += sA[rr];
      sB[rr] = hexp2(sB[rr]); vsum += sB[rr];
    }
    lrun += vsum;

    // cvt_pk + permlane32_swap -> P^T B-frags into wc
    #pragma unroll
    for (int g = 0; g < 2; ++g) {
      #pragma unroll
      for (int fs = 0; fs < 2; ++fs) {
        int b0 = fs * 8;
        float e0, e1, e2, e3, e4, e5, e6, e7;
        if (g == 0) {
          e0 = sA[b0+0]; e1 = sA[b0+1]; e2 = sA[b0+2]; e3 = sA[b0+3];
          e4 = sA[b0+4]; e5 = sA[b0+5]; e6 = sA[b0+6]; e7 = sA[b0+7];
        } else {
          e0 = sB[b0+0]; e1 = sB[b0+1]; e2 = sB[b0+2]; e3 = sB[b0+3];
          e4 = sB[b0+4]; e5 = sB[b0+5]; e6 = sB[b0+6]; e7 = sB[b0+7];
        }
        unsigned X1, X2, Y1, Y2;
        asm("v_cvt_pk_bf16_f32 %0, %1, %2" : "=v"(X1) : "v"(e0), "v"(e1));
        asm("v_cvt_pk_bf16_f32 %0, %1, %2" : "=v"(X2) : "v"(e2), "v"(e3));
        asm("v_cvt_pk_bf16_f32 %0, %1, %2" : "=v"(Y1) : "v"(e4), "v"(e5));
        asm("v_cvt_pk_bf16_f32 %0, %1, %2" : "=v"(Y2) : "v"(e6), "v"(e7));
        asm("v_permlane32_swap_b32 %0, %1" : "+v"(X1), "+v"(Y1));
        asm("v_permlane32_swap_b32 %0, %1" : "+v"(X2), "+v"(Y2));
        int kst = g * 2 + fs;
        wc[kst][0] = X1; wc[kst][1] = X2; wc[kst][2] = Y1; wc[kst][3] = Y2;
      }
    }
  };

  // deferred PV(kt): V-frags from Vbuf[kt&3] (DMA completed 2 regions ago), P from wp.
  // Independent of the current region's softmax chain -> scheduler interleaves.
  auto pvpart = [&](int kt, unsigned (&wp)[4][4]) {
    const short* Vc = VbufR + (kt & 3) * 4096;
    bf16x8 vf0[4], vf1[4];
    #pragma unroll
    for (int s = 0; s < 4; ++s) {
      vf0[s] = *(const bf16x8*)&Vc[(0 * 4 + s) * 512 + lane * 8];
      vf1[s] = *(const bf16x8*)&Vc[(4 + s) * 512 + lane * 8];
    }
    __builtin_amdgcn_s_setprio(1);
    #pragma unroll
    for (int kst = 0; kst < 4; ++kst) {
      union { unsigned u[4]; bf16x8 v; } bw;
      bw.u[0] = wp[kst][0]; bw.u[1] = wp[kst][1]; bw.u[2] = wp[kst][2]; bw.u[3] = wp[kst][3];
      o0 = __builtin_amdgcn_mfma_f32_32x32x16_bf16(vf0[kst], bw.v, o0, 0, 0, 0);
      o1 = __builtin_amdgcn_mfma_f32_32x32x16_bf16(vf1[kst], bw.v, o1, 0, 0, 0);
    }
    __builtin_amdgcn_s_setprio(0);
  };

  qkpart(0, wA);                    // region 0: no PV yet
  #pragma unroll 1
  for (int i = 0; i < 16; ++i) {    // kt = 1..32 in pairs; PV lags by one region
    qkpart(2 * i + 1, wB);
    pvpart(2 * i,     wA);
    qkpart(2 * i + 2, wA);
    pvpart(2 * i + 1, wB);
  }
  pvpart(32, wA);                   // tail: V(32) in Vbuf[0], staged & drained

  lrun += __shfl_xor(lrun, 32, 64);   // fold the two lane-halves of each q-column

  // epilogue: normalized bf16 write, TILED layout for the out-GEMM (row space b*N_+n)
  int qrow = q0 + q;
  if (qrow < N_) {
    float inv = 1.0f / lrun;
    int grow = b * N_ + qrow;
    #pragma unroll
    for (int m = 0; m < 2; ++m) {
      #pragma unroll
      for (int gq = 0; gq < 4; ++gq) {
        float a0 = (m ? o1[gq*4+0] : o0[gq*4+0]) * inv;
        float a1 = (m ? o1[gq*4+1] : o0[gq*4+1]) * inv;
        float a2 = (m ? o1[gq*4+2] : o0[gq*4+2]) * inv;
        float a3 = (m ? o1[gq*4+3] : o0[gq*4+3]) * inv;
        short4 st;
        st.x = f2bf(a0); st.y = f2bf(a1); st.z = f2bf(a2); st.w = f2bf(a3);
        int dh = m * 32 + gq * 8 + half * 4;
        *(short4*)(out + tiled_off(grow, h * DH + dh)) = st;
      }
    }
  }
}

// ---------------- launcher ----------------
extern "C" void kernel_launch(void* const* d_in, const int* in_sizes, int n_in,
                              void* d_out, int out_size, void* d_ws, size_t ws_size,
                              hipStream_t stream) {
  const float* x     = (const float*)d_in[0];
  const float* gamma = (const float*)d_in[1];
  const float* beta  = (const float*)d_in[2];
  const float* w_qkv = (const float*)d_in[3];
  const float* w_out = (const float*)d_in[4];

  short* wqkvT = (short*)d_ws;                         // tiled [24 panels]
  short* woutT = wqkvT + (size_t)3072 * 1024;          // tiled [8 panels]
  short* xn    = woutT + (size_t)1024 * 1024;          // tiled [33 panels], rows b*NPAD+n
  short* qg    = xn    + (size_t)MPAD * 1024;          // [2][16][2112][64]
  short* kfragG = qg    + (size_t)B_ * H_ * NPAD * DH; // fragment-linear K
  short* vfragG = kfragG + (size_t)B_ * H_ * NPAD * DH;// fragment-linear V^T
  short* attn_out = xn;                                // xn dead after fused QKV GEMM

  // ln (4098) + transpose wqkv (768) + transpose wout (256) in one dispatch
  prep_kernel<<<MROWS + 768 + 256, 256, 0, stream>>>(x, gamma, beta, xn,
                                                     w_qkv, wqkvT, w_out, woutT);
  // fused QKV GEMM + RoPE + fragment emission: 792 blocks (%8==0), XCD-swizzled
  gemm_qkv_rope<<<792, 256, 0, stream>>>(xn, wqkvT, qg, kfragG, vfragG);
  // full-K attention: 544 wg x 4 waves; deferred-PV pipeline; normalized tiled output
  attn_kernel<<<544, 256, 0, stream>>>(qg, kfragG, vfragG, attn_out);
  // out GEMM: 66x8 = 528 blocks (%8==0), XCD-swizzled inside
  gemm_out<<<528, 256, 0, stream>>>(attn_out, woutT, (float*)d_out);
}

// Round 17
// 209.263 us; speedup vs baseline: 1.0779x; 1.0779x over previous
//
#include <hip/hip_runtime.h>

// ---- problem constants ----
#define B_    2
#define N_    2049
#define NPAD  2112          // keys padded to multiple of 64
#define D_    1024
#define H_    16
#define DH    64
#define MROWS (B_ * N_)     // 4098
#define MPAD  4224          // = 2*NPAD: per-batch padded row space [b][NPAD]
#define QSCALE 0.18033688011117674f   // 0.125 * log2(e): softmax in exp2 domain

using bf16x8 = __attribute__((ext_vector_type(8))) short;
using f32x4  = __attribute__((ext_vector_type(4))) float;
using f32x16 = __attribute__((ext_vector_type(16))) float;

#define AS1 __attribute__((address_space(1)))
#define AS3 __attribute__((address_space(3)))

__device__ __forceinline__ float bf2f(short s) {
  union { unsigned u; float f; } a; a.u = ((unsigned)(unsigned short)s) << 16; return a.f;
}
__device__ __forceinline__ short f2bf(float f) {
  union { float f; unsigned u; } a; a.f = f;
  unsigned r = a.u + 0x7fffu + ((a.u >> 16) & 1u);   // round-to-nearest-even
  return (short)(r >> 16);
}
// hardware 2^x (v_exp_f32)
__device__ __forceinline__ float hexp2(float x) { return __builtin_amdgcn_exp2f(x); }
// async global->LDS DMA, 16 B/lane; LDS dst is wave-uniform base (+lane*16 by HW)
__device__ __forceinline__ void dma16(const short* g, AS3 short* l) {
  __builtin_amdgcn_global_load_lds((const AS1 unsigned*)g, (AS3 unsigned*)l, 16, 0, 0);
}

// ---- panel-tiled layout for GEMM operands (K=1024 fixed) ----
// X[m][k] -> [m>>7][k>>5][(m&127)>>4][((m&15)<<2)|((k&31)>>3)][k&7]
__device__ __forceinline__ size_t tiled_off(int m, int k) {
  return ((size_t)(m >> 7) << 17)                       // panel: 128*1024 shorts
       + (size_t)(((k >> 5) << 12)                      // kt chunk: 4096 shorts
       + ((((m & 127) >> 4)) << 9)                      // j slab: 512 shorts
       + (((((m & 15) << 2) | ((k & 31) >> 3))) << 3)   // lane slot: 8 shorts
       + (k & 7));
}

// ------------- prep: ln (4098 blks) + transpose wqkv (768) + transpose wout (256) --------
// LN writes xn in PER-BATCH padded rows: row' = b*NPAD + n (pad rows left stale; the
// fused gemm epilogue zero-emits n>=N_, so stale pads never reach attn).
__global__ __launch_bounds__(256) void prep_kernel(const float* __restrict__ x,
                                                   const float* __restrict__ gamma,
                                                   const float* __restrict__ beta,
                                                   short* __restrict__ xn,
                                                   const float* __restrict__ w_qkv,
                                                   short* __restrict__ wqkvT,
                                                   const float* __restrict__ w_out,
                                                   short* __restrict__ woutT) {
  int blk = blockIdx.x;
  int tid = threadIdx.x;
  __shared__ float T[64][65];
  __shared__ float sb[4], s2b[4];

  if (blk < MROWS) {
    // ---- LayerNorm row ----
    int row = blk;
    int b = row >= N_;
    int rowp = b * NPAD + (row - b * N_);
    const float4 v = ((const float4*)(x + (size_t)row * D_))[tid];
    float s  = v.x + v.y + v.z + v.w;
    float ss = v.x * v.x + v.y * v.y + v.z * v.z + v.w * v.w;
    for (int o = 1; o < 64; o <<= 1) { s += __shfl_xor(s, o, 64); ss += __shfl_xor(ss, o, 64); }
    int wid = tid >> 6;
    if ((tid & 63) == 0) { sb[wid] = s; s2b[wid] = ss; }
    __syncthreads();
    float st  = sb[0] + sb[1] + sb[2] + sb[3];
    float sst = s2b[0] + s2b[1] + s2b[2] + s2b[3];
    float mu  = st * (1.0f / D_);
    float var = sst * (1.0f / D_) - mu * mu;
    float rs  = rsqrtf(var + 1e-5f);
    const float4 g  = ((const float4*)gamma)[tid];
    const float4 be = ((const float4*)beta)[tid];
    short4 o4;
    o4.x = f2bf((v.x - mu) * rs * g.x + be.x);
    o4.y = f2bf((v.y - mu) * rs * g.y + be.y);
    o4.z = f2bf((v.z - mu) * rs * g.z + be.z);
    o4.w = f2bf((v.w - mu) * rs * g.w + be.w);
    *(short4*)(xn + tiled_off(rowp, tid * 4)) = o4;   // tiled write (8B, aligned)
    return;
  }

  // ---- transpose+cast: fp32 [K][Nn] -> bf16 tiled [Nn][K], 64x64 LDS tile ----
  const float* in; short* out; int Nn, t2;
  int b2 = blk - MROWS;
  if (b2 < 768) { in = w_qkv; out = wqkvT; Nn = 3072; t2 = b2; }
  else          { in = w_out; out = woutT; Nn = 1024; t2 = b2 - 768; }
  int k0 = (t2 & 15) * 64;          // 1024/64 = 16 tiles along K
  int n0 = (t2 >> 4) * 64;
  int r = tid >> 2, c0 = (tid & 3) * 16;
  const float* ip = in + (size_t)(k0 + r) * Nn + n0 + c0;
  #pragma unroll
  for (int j = 0; j < 4; ++j) {
    float4 v = *(const float4*)(ip + j * 4);
    T[r][c0 + j * 4 + 0] = v.x; T[r][c0 + j * 4 + 1] = v.y;
    T[r][c0 + j * 4 + 2] = v.z; T[r][c0 + j * 4 + 3] = v.w;
  }
  __syncthreads();
  bf16x8 w0, w1;
  #pragma unroll
  for (int j = 0; j < 8; ++j) {
    w0[j] = f2bf(T[c0 + j][r]);
    w1[j] = f2bf(T[c0 + 8 + j][r]);
  }
  *(bf16x8*)(out + tiled_off(n0 + r, k0 + c0))     = w0;   // tiled writes (16B, aligned)
  *(bf16x8*)(out + tiled_off(n0 + r, k0 + c0 + 8)) = w1;
}

// ------------- fused QKV GEMM + RoPE + fragment emission -------------
// Mainloop = r11's verified 128x128 tiled-operand GEMM. Epilogue: stage C-tile to LDS
// (aliasing the dead A/B staging buffers, stride 136 shorts), then emit directly:
//   nb/8==0 -> qg row-major (rotated, *QSCALE); ==1 -> kfrag (rotated); ==2 -> vfrag.
// Rows are in per-batch padded space (b*NPAD+n); n>=N_ emits ZEROS.
#define BM 128
#define BK 32
__global__ __launch_bounds__(256) void gemm_qkv_rope(const short* __restrict__ A,
                                                     const short* __restrict__ BT,
                                                     short* __restrict__ qg,
                                                     short* __restrict__ kfrag,
                                                     short* __restrict__ vfrag) {
  int lane = threadIdx.x & 63, wid = threadIdx.x >> 6;
  int quad = lane >> 4, l16 = lane & 15;
  int wr = wid >> 1, wc = wid & 1;
  int chunk = gridDim.x >> 3;
  int swz = (blockIdx.x & 7) * chunk + (blockIdx.x >> 3);
  int mb = swz % 33, nb = swz / 33;     // nb 0..23
  int m0 = mb * BM;
  int n0 = nb * BM;

  __shared__ __align__(16) short pool[17408];   // mainloop: A[2][4096]+B[2][4096]; epi: Ct[128][136]
  AS3 short* AbufL = (AS3 short*)pool;
  AS3 short* BbufL = (AS3 short*)(pool + 8192);
  const short* AbufR = pool;
  const short* BbufR = pool + 8192;

  f32x4 acc[4][4] = {};

  const short* Ap = A  + ((size_t)(m0 >> 7) << 17);   // panel bases
  const short* Bp = BT + ((size_t)(n0 >> 7) << 17);

  auto stage = [&](int kt, int bb) {
    #pragma unroll
    for (int i = 0; i < 2; ++i) {
      int j = wid * 2 + i;                  // slab 0..7 (16 rows each)
      dma16(Ap + ((size_t)kt << 12) + j * 512 + lane * 8, AbufL + bb * 4096 + j * 512);
      dma16(Bp + ((size_t)kt << 12) + j * 512 + lane * 8, BbufL + bb * 4096 + j * 512);
    }
  };

  stage(0, 0);
  __syncthreads();

  for (int kt = 0; kt < 32; ++kt) {
    int cur = kt & 1;
    if (kt + 1 < 32) stage(kt + 1, cur ^ 1);
    const short* Ab = AbufR + cur * 4096;
    const short* Bb = BbufR + cur * 4096;
    bf16x8 af[4], bfr[4];
    #pragma unroll
    for (int s = 0; s < 4; ++s)
      af[s] = *(const bf16x8*)&Ab[(wr * 64 + s * 16 + l16) * BK + quad * 8];
    #pragma unroll
    for (int t = 0; t < 4; ++t)
      bfr[t] = *(const bf16x8*)&Bb[(wc * 64 + t * 16 + l16) * BK + quad * 8];
    #pragma unroll
    for (int s = 0; s < 4; ++s)
      #pragma unroll
      for (int t = 0; t < 4; ++t)
        acc[s][t] = __builtin_amdgcn_mfma_f32_16x16x32_bf16(af[s], bfr[t], acc[s][t], 0, 0, 0);
    __syncthreads();
  }

  // ---- stage C tile (bf16) to LDS: Ct[row][col], stride 136 shorts ----
  short* Ct = pool;     // A/B buffers dead after final barrier
  #pragma unroll
  for (int s = 0; s < 4; ++s)
    #pragma unroll
    for (int t = 0; t < 4; ++t) {
      int col = wc * 64 + t * 16 + l16;
      #pragma unroll
      for (int r = 0; r < 4; ++r) {
        int row = wr * 64 + s * 16 + quad * 4 + r;
        Ct[row * 136 + col] = f2bf(acc[s][t][r]);
      }
    }
  __syncthreads();

  int third = nb >> 3;            // 0=q 1=k 2=v
  int hpair = (nb & 7) * 2;       // head base (2 heads per block)
  int tid = threadIdx.x;

  if (third == 0) {
    // ---- Q: rope + scale, row-major qg[bh][n][dh] ----
    int p = tid & 3, nl = tid >> 2;
    #pragma unroll
    for (int tt = 0; tt < 2; ++tt) {
      int rl = tt * 64 + nl;
      int rg = m0 + rl;
      int b = rg >= NPAD;
      int n = rg - b * NPAD;
      bool valid = n < N_;
      bool rot = valid && n > 0;
      float csv[8], snv[8];
      #pragma unroll
      for (int j = 0; j < 8; ++j) {
        int i = p * 8 + j;
        float ang = rot ? (float)(n - 1) * hexp2((float)i * -0.4152410118609203f) : 0.0f;
        float rev = ang * 0.15915494309189535f;
        rev = rev - floorf(rev);
        snv[j] = rot ? __builtin_amdgcn_sinf(rev) : 0.0f;
        csv[j] = rot ? __builtin_amdgcn_cosf(rev) : 1.0f;
      }
      #pragma unroll
      for (int hh = 0; hh < 2; ++hh) {
        bf16x8 w1v = {}, w2v = {};
        if (valid) {
          bf16x8 va = *(const bf16x8*)&Ct[rl * 136 + hh * 64 + p * 8];
          bf16x8 vb = *(const bf16x8*)&Ct[rl * 136 + hh * 64 + p * 8 + 32];
          #pragma unroll
          for (int j = 0; j < 8; ++j) {
            float a = bf2f(va[j]), b2 = bf2f(vb[j]);
            w1v[j] = f2bf((a * csv[j] - b2 * snv[j]) * QSCALE);
            w2v[j] = f2bf((b2 * csv[j] + a * snv[j]) * QSCALE);
          }
        }
        size_t ob = ((size_t)(b * 16 + hpair + hh) * NPAD + n) * DH;
        *(bf16x8*)(qg + ob + p * 8)      = w1v;
        *(bf16x8*)(qg + ob + 32 + p * 8) = w2v;
      }
    }
  } else if (third == 1) {
    // ---- K: rope, fragment-linear kfrag[bh][kt][g*4+s][l][8] = K[g*32+lk][s*16+hi*8+j] ----
    int rl = tid & 127, hi = tid >> 7;
    int rg = m0 + rl;
    int b = rg >= NPAD;
    int n = rg - b * NPAD;
    bool valid = n < N_;
    bool rot = valid && n > 0;
    int kt = n >> 6, g = (n >> 5) & 1, lk = n & 31;
    int l = hi * 32 + lk;
    #pragma unroll
    for (int s2 = 0; s2 < 2; ++s2) {
      float csv[8], snv[8];
      #pragma unroll
      for (int j = 0; j < 8; ++j) {
        int i = s2 * 16 + hi * 8 + j;            // i in [0,32)
        float ang = rot ? (float)(n - 1) * hexp2((float)i * -0.4152410118609203f) : 0.0f;
        float rev = ang * 0.15915494309189535f;
        rev = rev - floorf(rev);
        snv[j] = rot ? __builtin_amdgcn_sinf(rev) : 0.0f;
        csv[j] = rot ? __builtin_amdgcn_cosf(rev) : 1.0f;
      }
      #pragma unroll
      for (int hh = 0; hh < 2; ++hh) {
        bf16x8 wlo = {}, whi = {};
        if (valid) {
          bf16x8 va = *(const bf16x8*)&Ct[rl * 136 + hh * 64 + s2 * 16 + hi * 8];
          bf16x8 vb = *(const bf16x8*)&Ct[rl * 136 + hh * 64 + s2 * 16 + hi * 8 + 32];
          #pragma unroll
          for (int j = 0; j < 8; ++j) {
            float a = bf2f(va[j]), b2 = bf2f(vb[j]);
            wlo[j] = f2bf(a * csv[j] - b2 * snv[j]);
            whi[j] = f2bf(b2 * csv[j] + a * snv[j]);
          }
        }
        short* base = kfrag + (size_t)(b * 16 + hpair + hh) * NPAD * DH + (size_t)kt * 4096;
        *(bf16x8*)(base + (g * 4 + s2) * 512 + l * 8)     = wlo;
        *(bf16x8*)(base + (g * 4 + s2 + 2) * 512 + l * 8) = whi;
      }
    }
  } else {
    // ---- V: fragment-linear vfrag[bh][kt][m*4+s][hi*32+lk][j] = V[key octet+j][m*32+lk] ----
    int lk = tid & 31, z = tid >> 5;   // z 0..7
    #pragma unroll
    for (int oo = 0; oo < 2; ++oo) {
      int o = z * 2 + oo;              // key octet 0..15 within block
      int rg = m0 + o * 8;
      int b = rg >= NPAD;
      int n0o = rg - b * NPAD;         // octet-base key index (8-aligned)
      int kt = n0o >> 6;
      int s = (n0o >> 4) & 3;
      int hi = (n0o >> 3) & 1;
      #pragma unroll
      for (int hh = 0; hh < 2; ++hh) {
        short* base = vfrag + (size_t)(b * 16 + hpair + hh) * NPAD * DH + (size_t)kt * 4096;
        #pragma unroll
        for (int m = 0; m < 2; ++m) {
          bf16x8 wv = {};
          #pragma unroll
          for (int j = 0; j < 8; ++j)
            if (n0o + j < N_) wv[j] = Ct[(o * 8 + j) * 136 + hh * 64 + m * 32 + lk];
          *(bf16x8*)(base + (m * 4 + s) * 512 + (hi * 32 + lk) * 8) = wv;
        }
      }
    }
  }
}

// ------------- m97-style 128x128 GEMM (out-proj), TILED A, XCD-swizzled 1D grid ----------
template <typename OutT>
__global__ __launch_bounds__(256) void gemm128(const short* __restrict__ A,
                                               const short* __restrict__ BT,
                                               OutT* __restrict__ C,
                                               int Mstore, int Ncols, int K) {
  int lane = threadIdx.x & 63, wid = threadIdx.x >> 6;
  int quad = lane >> 4, l16 = lane & 15;
  int wr = wid >> 1, wc = wid & 1;
  int chunk = gridDim.x >> 3;
  int swz = (blockIdx.x & 7) * chunk + (blockIdx.x >> 3);
  int mb = swz % 33, nb = swz / 33;
  int m0 = mb * BM;
  int n0 = nb * BM;

  __shared__ __align__(16) short Abuf[2][BM * BK];   // 8 KB each
  __shared__ __align__(16) short Bbuf[2][BM * BK];
  AS3 short* AbufL = (AS3 short*)&Abuf[0][0];
  AS3 short* BbufL = (AS3 short*)&Bbuf[0][0];

  f32x4 acc[4][4] = {};

  const short* Ap = A  + ((size_t)(m0 >> 7) << 17);   // panel bases
  const short* Bp = BT + ((size_t)(n0 >> 7) << 17);

  auto stage = [&](int kt, int bb) {
    #pragma unroll
    for (int i = 0; i < 2; ++i) {
      int j = wid * 2 + i;                  // slab 0..7 (16 rows each)
      dma16(Ap + ((size_t)kt << 12) + j * 512 + lane * 8, AbufL + bb * (BM * BK) + j * 512);
      dma16(Bp + ((size_t)kt << 12) + j * 512 + lane * 8, BbufL + bb * (BM * BK) + j * 512);
    }
  };

  stage(0, 0);
  __syncthreads();

  int KT = K / BK;
  for (int kt = 0; kt < KT; ++kt) {
    int cur = kt & 1;
    if (kt + 1 < KT) stage(kt + 1, cur ^ 1);
    const short* Ab = &Abuf[cur][0];
    const short* Bb = &Bbuf[cur][0];
    bf16x8 af[4], bfr[4];
    #pragma unroll
    for (int s = 0; s < 4; ++s)
      af[s] = *(const bf16x8*)&Ab[(wr * 64 + s * 16 + l16) * BK + quad * 8];
    #pragma unroll
    for (int t = 0; t < 4; ++t)
      bfr[t] = *(const bf16x8*)&Bb[(wc * 64 + t * 16 + l16) * BK + quad * 8];
    #pragma unroll
    for (int s = 0; s < 4; ++s)
      #pragma unroll
      for (int t = 0; t < 4; ++t)
        acc[s][t] = __builtin_amdgcn_mfma_f32_16x16x32_bf16(af[s], bfr[t], acc[s][t], 0, 0, 0);
    __syncthreads();
  }

  #pragma unroll
  for (int s = 0; s < 4; ++s)
    #pragma unroll
    for (int r = 0; r < 4; ++r) {
      int row = m0 + wr * 64 + s * 16 + quad * 4 + r;
      if (row < Mstore) {
        size_t rb = (size_t)row * Ncols + n0 + wc * 64;
        #pragma unroll
        for (int t = 0; t < 4; ++t) {
          float val = acc[s][t][r];
          if constexpr (sizeof(OutT) == 2)
            C[rb + t * 16 + l16] = (OutT)(unsigned short)f2bf(val);
          else
            C[rb + t * 16 + l16] = (OutT)val;
        }
      }
    }
}

// ------------- flash attention (r13-exact): full-K, DMA-staged K+V, in-reg softmax --------
// The residency/ILP local optimum: 544 x 4-wave blocks, triple-buffer, counted vmcnt(4),
// VGPR 68, LDS 49KB. Three falsified alternatives (r8 launch-bounds, r14 2-wave, r16
// deferred-PV) all lost more TLP than they gained.
__global__ __launch_bounds__(256, 3) void attn_kernel(const short* __restrict__ qg,
                                                      const short* __restrict__ kfrag,
                                                      const short* __restrict__ vfrag,
                                                      short* __restrict__ out) {
  // XCD-clustered decode: blk&7 -> XCD; 4 heads per XCD
  int blk = blockIdx.x;             // 0..543
  int xcd = blk & 7;
  int t_  = blk >> 3;               // 0..67
  int bh  = xcd * 4 + (t_ & 3);
  int qblk = t_ >> 2;               // 0..16
  int b = bh >> 4, h = bh & 15;

  int lane = threadIdx.x & 63, wid = threadIdx.x >> 6;
  int q    = lane & 31;             // q-column within wave's 32-row tile
  int half = lane >> 5;             // 0/1: lane half
  int q0   = qblk * 128 + wid * 32;
  size_t hb = (size_t)bh * NPAD * DH;
  const short* kf_hb = kfrag + hb;
  const short* vf_hb = vfrag + hb;

  __shared__ __align__(16) short Kbuf[3][4096];   // 24 KB
  __shared__ __align__(16) short Vbuf[3][4096];   // 24 KB
  AS3 short* KbufL = (AS3 short*)&Kbuf[0][0];
  AS3 short* VbufL = (AS3 short*)&Vbuf[0][0];
  const short* KbufR = &Kbuf[0][0];
  const short* VbufR = &Vbuf[0][0];

  // Q B-frags (persistent): lane reads its q-row; k = kstep*16 + half*8 + j
  int qr = q0 + q; if (qr >= NPAD) qr = 0;   // clamp; garbage column never stored
  const short* qp = qg + hb + (size_t)qr * DH + half * 8;
  bf16x8 qf[4];
  #pragma unroll
  for (int s = 0; s < 4; ++s) qf[s] = *(const bf16x8*)(qp + s * 16);

  f32x16 o0 = {}, o1 = {};          // O^T[dh = m*32 + (reg&3)+8*(reg>>2)+4*half][q]
  float lrun = 0.0f;                // per-lane half-sum; cross-half fold at epilogue

  // K+V stage: fragment-linear, every DMA source contiguous 1KiB. 4 ops/wave/stage.
  auto stage = [&](int kt, int bb) {
    const short* ksrc = kf_hb + (size_t)kt * 4096;
    const short* vsrc = vf_hb + (size_t)kt * 4096;
    #pragma unroll
    for (int i = 0; i < 2; ++i) {
      int j = wid * 2 + i;
      dma16(ksrc + j * 512 + lane * 8, KbufL + bb * 4096 + j * 512);
      dma16(vsrc + j * 512 + lane * 8, VbufL + bb * 4096 + j * 512);
    }
  };

  stage(0, 0);                      // prefetch distance 2
  stage(1, 1);

  #define NKT 33
  for (int kt = 0; kt < NKT; ++kt) {
    int rb = kt % 3;
    int k0 = kt * 64;

    if (kt == NKT - 1) asm volatile("s_waitcnt vmcnt(0)" ::: "memory");
    else               asm volatile("s_waitcnt vmcnt(4)" ::: "memory");
    __builtin_amdgcn_s_barrier();

    if (kt + 2 < NKT) stage(kt + 2, (kt + 2) % 3);
    __builtin_amdgcn_sched_barrier(0);

    // V A-frags from LDS (issued early; lgkm latency hidden under QK)
    const short* Vc = VbufR + rb * 4096;
    bf16x8 vf0[4], vf1[4];
    #pragma unroll
    for (int s = 0; s < 4; ++s) {
      vf0[s] = *(const bf16x8*)&Vc[(0 * 4 + s) * 512 + lane * 8];
      vf1[s] = *(const bf16x8*)&Vc[(4 + s) * 512 + lane * 8];
    }

    // ---- S^T = K * Q^T : two 32-key groups, 4 k-steps of 16 ----
    const short* Kc = KbufR + rb * 4096;
    f32x16 sA = {}, sB = {};
    __builtin_amdgcn_s_setprio(1);
    #pragma unroll
    for (int s = 0; s < 4; ++s) {
      bf16x8 kf0 = *(const bf16x8*)&Kc[(0 * 4 + s) * 512 + lane * 8];
      bf16x8 kf1 = *(const bf16x8*)&Kc[(1 * 4 + s) * 512 + lane * 8];
      sA = __builtin_amdgcn_mfma_f32_32x32x16_bf16(kf0, qf[s], sA, 0, 0, 0);
      sB = __builtin_amdgcn_mfma_f32_32x32x16_bf16(kf1, qf[s], sB, 0, 0, 0);
    }
    __builtin_amdgcn_s_setprio(0);

    // mask invalid keys (final tile only; wave-uniform branch)
    if (k0 + 64 > N_) {
      #pragma unroll
      for (int rr = 0; rr < 16; ++rr) {
        int key = (rr & 3) + 8 * (rr >> 2) + 4 * half;
        if (k0 + key >= N_)      sA[rr] = -1e30f;
        if (k0 + 32 + key >= N_) sB[rr] = -1e30f;
      }
    }

    // ---- p = 2^s in place + per-lane row-sum ----
    float vsum = 0.0f;
    #pragma unroll
    for (int rr = 0; rr < 16; ++rr) {
      sA[rr] = hexp2(sA[rr]); vsum += sA[rr];
      sB[rr] = hexp2(sB[rr]); vsum += sB[rr];
    }
    lrun += vsum;

    // ---- cvt_pk pairs + permlane32_swap -> P^T B-frags, all in registers ----
    unsigned w[4][4];
    #pragma unroll
    for (int g = 0; g < 2; ++g) {
      #pragma unroll
      for (int fs = 0; fs < 2; ++fs) {
        int b0 = fs * 8;
        float e0, e1, e2, e3, e4, e5, e6, e7;
        if (g == 0) {
          e0 = sA[b0+0]; e1 = sA[b0+1]; e2 = sA[b0+2]; e3 = sA[b0+3];
          e4 = sA[b0+4]; e5 = sA[b0+5]; e6 = sA[b0+6]; e7 = sA[b0+7];
        } else {
          e0 = sB[b0+0]; e1 = sB[b0+1]; e2 = sB[b0+2]; e3 = sB[b0+3];
          e4 = sB[b0+4]; e5 = sB[b0+5]; e6 = sB[b0+6]; e7 = sB[b0+7];
        }
        unsigned X1, X2, Y1, Y2;
        asm("v_cvt_pk_bf16_f32 %0, %1, %2" : "=v"(X1) : "v"(e0), "v"(e1));
        asm("v_cvt_pk_bf16_f32 %0, %1, %2" : "=v"(X2) : "v"(e2), "v"(e3));
        asm("v_cvt_pk_bf16_f32 %0, %1, %2" : "=v"(Y1) : "v"(e4), "v"(e5));
        asm("v_cvt_pk_bf16_f32 %0, %1, %2" : "=v"(Y2) : "v"(e6), "v"(e7));
        asm("v_permlane32_swap_b32 %0, %1" : "+v"(X1), "+v"(Y1));
        asm("v_permlane32_swap_b32 %0, %1" : "+v"(X2), "+v"(Y2));
        int kst = g * 2 + fs;
        w[kst][0] = X1; w[kst][1] = X2; w[kst][2] = Y1; w[kst][3] = Y2;
      }
    }

    // ---- O^T += V^T * P^T ----
    __builtin_amdgcn_s_setprio(1);
    #pragma unroll
    for (int kst = 0; kst < 4; ++kst) {
      union { unsigned u[4]; bf16x8 v; } bw;
      bw.u[0] = w[kst][0]; bw.u[1] = w[kst][1]; bw.u[2] = w[kst][2]; bw.u[3] = w[kst][3];
      o0 = __builtin_amdgcn_mfma_f32_32x32x16_bf16(vf0[kst], bw.v, o0, 0, 0, 0);
      o1 = __builtin_amdgcn_mfma_f32_32x32x16_bf16(vf1[kst], bw.v, o1, 0, 0, 0);
    }
    __builtin_amdgcn_s_setprio(0);
    // no trailing barrier: top-of-loop guard+barrier covers buffer reuse
  }

  lrun += __shfl_xor(lrun, 32, 64);   // fold the two lane-halves of each q-column

  // epilogue: normalized bf16 write, TILED layout for the out-GEMM (row space b*N_+n)
  int qrow = q0 + q;
  if (qrow < N_) {
    float inv = 1.0f / lrun;
    int grow = b * N_ + qrow;
    #pragma unroll
    for (int m = 0; m < 2; ++m) {
      #pragma unroll
      for (int gq = 0; gq < 4; ++gq) {
        float a0 = (m ? o1[gq*4+0] : o0[gq*4+0]) * inv;
        float a1 = (m ? o1[gq*4+1] : o0[gq*4+1]) * inv;
        float a2 = (m ? o1[gq*4+2] : o0[gq*4+2]) * inv;
        float a3 = (m ? o1[gq*4+3] : o0[gq*4+3]) * inv;
        short4 st;
        st.x = f2bf(a0); st.y = f2bf(a1); st.z = f2bf(a2); st.w = f2bf(a3);
        int dh = m * 32 + gq * 8 + half * 4;
        *(short4*)(out + tiled_off(grow, h * DH + dh)) = st;
      }
    }
  }
}

// ---------------- launcher ----------------
extern "C" void kernel_launch(void* const* d_in, const int* in_sizes, int n_in,
                              void* d_out, int out_size, void* d_ws, size_t ws_size,
                              hipStream_t stream) {
  const float* x     = (const float*)d_in[0];
  const float* gamma = (const float*)d_in[1];
  const float* beta  = (const float*)d_in[2];
  const float* w_qkv = (const float*)d_in[3];
  const float* w_out = (const float*)d_in[4];

  short* wqkvT = (short*)d_ws;                         // tiled [24 panels]
  short* woutT = wqkvT + (size_t)3072 * 1024;          // tiled [8 panels]
  short* xn    = woutT + (size_t)1024 * 1024;          // tiled [33 panels], rows b*NPAD+n
  short* qg    = xn    + (size_t)MPAD * 1024;          // [2][16][2112][64]
  short* kfragG = qg    + (size_t)B_ * H_ * NPAD * DH; // fragment-linear K
  short* vfragG = kfragG + (size_t)B_ * H_ * NPAD * DH;// fragment-linear V^T
  short* attn_out = xn;                                // xn dead after fused QKV GEMM

  // ln (4098) + transpose wqkv (768) + transpose wout (256) in one dispatch
  prep_kernel<<<MROWS + 768 + 256, 256, 0, stream>>>(x, gamma, beta, xn,
                                                     w_qkv, wqkvT, w_out, woutT);
  // fused QKV GEMM + RoPE + fragment emission: 792 blocks (%8==0), XCD-swizzled
  gemm_qkv_rope<<<792, 256, 0, stream>>>(xn, wqkvT, qg, kfragG, vfragG);
  // full-K attention: 544 wg x 4 waves; writes normalized tiled output
  attn_kernel<<<544, 256, 0, stream>>>(qg, kfragG, vfragG, attn_out);
  // out GEMM: 1D grid 33x8=264 (%8==0), XCD-swizzled inside
  gemm128<float><<<264, 256, 0, stream>>>(attn_out, woutT, (float*)d_out, MROWS, 1024, 1024);
}